// Round 1
// baseline (680.137 us; speedup 1.0000x reference)
//
#include <hip/hip_runtime.h>
#include <hip/hip_bf16.h>
#include <math.h>

#define NQ 12
#define DIMK 256
#define NCTRL 25
#define TPB 256
#define PTS_PER_BLK 256   // 64 groups of 4 lanes, 4 points per group

// 4 lanes per point-group, 4 points per lane. Lane r handles k-slice
// {r*4 + i*16 .. +3} for i=0..15 (64 floats) of 4 consecutive points.
// Per-group global reads are 64B contiguous -> full cacheline use, each
// emb byte fetched exactly once (512 MB stream).
__global__ __launch_bounds__(TPB, 4) void kan_bspline_kernel(
    const float* __restrict__ emb,
    const float* __restrict__ W,
    const float* __restrict__ b_inner,
    const float* __restrict__ inner_scale,
    const float* __restrict__ coeffs,
    const float* __restrict__ a_out,
    const float* __restrict__ b_out,
    float* __restrict__ out,
    int n)
{
    __shared__ __align__(16) float sW[NQ * DIMK];   // 12 KB
    __shared__ float sC[NQ * NCTRL];                // 1.2 KB

    // stage W (768 float4) and coeffs (300 floats), coalesced
    for (int i = threadIdx.x; i < NQ * DIMK / 4; i += TPB)
        ((float4*)sW)[i] = ((const float4*)W)[i];
    for (int i = threadIdx.x; i < NQ * NCTRL; i += TPB)
        sC[i] = coeffs[i];
    __syncthreads();

    const int lane_r = threadIdx.x & 3;
    const int grp    = threadIdx.x >> 2;
    const int p0     = blockIdx.x * PTS_PER_BLK + grp * 4;
    const int nm1    = n - 1;

    float acc[NQ][4];
    #pragma unroll
    for (int q = 0; q < NQ; ++q)
        #pragma unroll
        for (int p = 0; p < 4; ++p)
            acc[q][p] = 0.0f;

    // K loop: 16 chunks of 16 bytes per lane per point
    #pragma unroll 4
    for (int i = 0; i < 16; ++i) {
        const int k = lane_r * 4 + i * 16;
        float4 e[4];
        #pragma unroll
        for (int p = 0; p < 4; ++p) {
            int pi = p0 + p;
            pi = pi > nm1 ? nm1 : pi;   // clamp: safe read, result discarded
            e[p] = *(const float4*)(emb + (size_t)pi * DIMK + k);
        }
        #pragma unroll
        for (int q = 0; q < NQ; ++q) {
            float4 w = *(const float4*)(sW + q * DIMK + k);
            #pragma unroll
            for (int p = 0; p < 4; ++p) {
                acc[q][p] += e[p].x * w.x;
                acc[q][p] += e[p].y * w.y;
                acc[q][p] += e[p].z * w.z;
                acc[q][p] += e[p].w * w.w;
            }
        }
    }

    // Reduce-SCATTER across the 4-lane group: lane r ends with the full
    // 12 inner sums for point p0+r (epilogue then runs once per point).
    float u[NQ];
    #pragma unroll
    for (int q = 0; q < NQ; ++q) {
        float s0 = acc[q][0] + __shfl_xor(acc[q][0], 1);
        float s1 = acc[q][1] + __shfl_xor(acc[q][1], 1);
        float s2 = acc[q][2] + __shfl_xor(acc[q][2], 1);
        float s3 = acc[q][3] + __shfl_xor(acc[q][3], 1);
        float x = (lane_r & 1) ? s1 : s0;
        float y = (lane_r & 1) ? s3 : s2;
        x += __shfl_xor(x, 2);
        y += __shfl_xor(y, 2);
        u[q] = (lane_r & 2) ? y : x;
    }

    const int n_idx = p0 + lane_r;
    if (n_idx < n) {
        const float scale = inner_scale[0];
        const float h   = 1.0f / 22.0f;
        const float i1h = 22.0f;
        const float i2h = 11.0f;
        const float i3h = 22.0f / 3.0f;
        float result = b_out[0];

        for (int q = 0; q < NQ; ++q) {
            float uu = u[q] + b_inner[q];
            float s = 0.5f * tanhf(scale * uu) + 0.5f;   // in [0,1]

            // interval: spans j=3..24 <-> iv=0..21, each width h
            int iv = (int)(s * 22.0f);
            iv = iv > 21 ? 21 : iv;
            iv = iv < 0 ? 0 : iv;
            float fiv = (float)iv;

            // left[r] = s - knot(j+1-r), right[r] = knot(j+r) - s
            // knot(m) = clamp((m-3)/22, 0, 1)
            float l1 = s - fiv * h;
            float l2 = s - fmaxf(fiv - 1.0f, 0.0f) * h;
            float l3 = s - fmaxf(fiv - 2.0f, 0.0f) * h;
            float r1 = fminf((fiv + 1.0f) * h, 1.0f) - s;
            float r2 = fminf((fiv + 2.0f) * h, 1.0f) - s;
            float r3 = fminf((fiv + 3.0f) * h, 1.0f) - s;

            // reciprocal knot-span denominators (exact-span selects)
            float inv_b = (iv >= 1) ? i2h : i1h;                          // U[i+1]-U[i-1]
            float inv_c = (iv <= 20) ? i2h : i1h;                         // U[i+2]-U[i]
            float inv_d = (iv >= 2) ? i3h : ((iv >= 1) ? i2h : i1h);      // U[i+1]-U[i-2]
            float inv_e = (iv >= 1 && iv <= 20) ? i3h : i2h;              // U[i+2]-U[i-1]
            float inv_f = (iv <= 19) ? i3h : ((iv <= 20) ? i2h : i1h);    // U[i+3]-U[i]

            // Cox-de Boor (NURBS-book BasisFuns), degree 3
            float temp, saved;
            temp = i1h;                  // N0(=1) / (r1+l1) = 1/h
            float N0 = r1 * temp;
            float N1 = l1 * temp;
            // j = 2
            temp  = N0 * inv_b;
            N0    = r1 * temp;
            saved = l2 * temp;
            temp  = N1 * inv_c;
            N1    = saved + r2 * temp;
            float N2 = l1 * temp;
            // j = 3
            temp  = N0 * inv_d;
            N0    = r1 * temp;
            saved = l3 * temp;
            temp  = N1 * inv_e;
            N1    = saved + r2 * temp;
            saved = l2 * temp;
            temp  = N2 * inv_f;
            N2    = saved + r3 * temp;
            float N3 = l1 * temp;

            const float* cq = sC + q * NCTRL + iv;
            float phi = N0 * cq[0] + N1 * cq[1] + N2 * cq[2] + N3 * cq[3];
            result += a_out[q] * phi;
        }
        out[n_idx] = result;
    }
}

extern "C" void kernel_launch(void* const* d_in, const int* in_sizes, int n_in,
                              void* d_out, int out_size, void* d_ws, size_t ws_size,
                              hipStream_t stream) {
    const float* emb         = (const float*)d_in[0];
    const float* W           = (const float*)d_in[1];
    const float* b_inner     = (const float*)d_in[2];
    const float* inner_scale = (const float*)d_in[3];
    const float* coeffs      = (const float*)d_in[4];
    const float* a_out       = (const float*)d_in[5];
    const float* b_out       = (const float*)d_in[6];
    float* out = (float*)d_out;

    const int n = in_sizes[0] / DIMK;
    const int blocks = (n + PTS_PER_BLK - 1) / PTS_PER_BLK;
    kan_bspline_kernel<<<blocks, TPB, 0, stream>>>(
        emb, W, b_inner, inner_scale, coeffs, a_out, b_out, out, n);
}